// Round 1
// baseline (370.572 us; speedup 1.0000x reference)
//
#include <hip/hip_runtime.h>
#include <math.h>

#define IN_DIM 512
#define MID 32
#define OUT_DIM 512
#define BATCH 32
#define HW 4096  // 64*64

// One block per (b,c) plane: 4096 contiguous floats. 256 threads x 4 float4 = 4096 floats.
__global__ __launch_bounds__(256) void pool_kernel(const float* __restrict__ x,
                                                   float* __restrict__ pooled) {
    const int plane = blockIdx.x;  // 0 .. B*C-1
    const float4* xp = (const float4*)(x + (size_t)plane * HW);
    const int tid = threadIdx.x;

    float s = 0.f;
#pragma unroll
    for (int i = 0; i < 4; ++i) {
        float4 v = xp[tid + 256 * i];
        s += (v.x + v.y) + (v.z + v.w);
    }
    // wave (64-lane) reduction
#pragma unroll
    for (int off = 32; off > 0; off >>= 1) s += __shfl_down(s, off, 64);

    __shared__ float ws[4];
    if ((tid & 63) == 0) ws[tid >> 6] = s;
    __syncthreads();
    if (tid == 0) {
        float t = (ws[0] + ws[1]) + (ws[2] + ws[3]);
        pooled[plane] = t * (1.0f / (float)HW);
    }
}

// One block per batch row. Bottleneck (512->32, ReLU) then expansion (32->512, sigmoid).
__global__ __launch_bounds__(256) void mlp_kernel(const float* __restrict__ pooled,
                                                  const float* __restrict__ w1,
                                                  const float* __restrict__ b1,
                                                  const float* __restrict__ w2,
                                                  const float* __restrict__ b2,
                                                  float* __restrict__ out) {
    const int b = blockIdx.x;  // 0..31
    const int tid = threadIdx.x;

    __shared__ float sp[IN_DIM];
    __shared__ float sh[MID];

    sp[tid] = pooled[b * IN_DIM + tid];
    sp[tid + 256] = pooled[b * IN_DIM + tid + 256];
    __syncthreads();

    if (tid < MID) {
        float acc = b1[tid];
        const float4* wr = (const float4*)(w1 + tid * IN_DIM);
        const float4* spv = (const float4*)sp;
#pragma unroll 4
        for (int c = 0; c < IN_DIM / 4; ++c) {
            float4 w = wr[c];
            float4 p = spv[c];
            acc += w.x * p.x + w.y * p.y + w.z * p.z + w.w * p.w;
        }
        sh[tid] = fmaxf(acc, 0.f);
    }
    __syncthreads();

#pragma unroll
    for (int r = 0; r < 2; ++r) {
        const int o = tid + r * 256;
        float acc = b2[o];
        const float* wr = w2 + o * MID;
#pragma unroll
        for (int m = 0; m < MID; ++m) acc += sh[m] * wr[m];
        out[b * OUT_DIM + o] = 1.0f / (1.0f + expf(-acc));
    }
}

extern "C" void kernel_launch(void* const* d_in, const int* in_sizes, int n_in,
                              void* d_out, int out_size, void* d_ws, size_t ws_size,
                              hipStream_t stream) {
    const float* x  = (const float*)d_in[0];
    const float* w1 = (const float*)d_in[1];
    const float* b1 = (const float*)d_in[2];
    const float* w2 = (const float*)d_in[3];
    const float* b2 = (const float*)d_in[4];
    float* out = (float*)d_out;
    float* pooled = (float*)d_ws;  // BATCH*IN_DIM floats = 64 KiB

    pool_kernel<<<BATCH * IN_DIM, 256, 0, stream>>>(x, pooled);
    mlp_kernel<<<BATCH, 256, 0, stream>>>(pooled, w1, b1, w2, b2, out);
}

// Round 3
// 350.393 us; speedup vs baseline: 1.0576x; 1.0576x over previous
//
#include <hip/hip_runtime.h>
#include <math.h>

#define IN_DIM 512
#define MID 32
#define OUT_DIM 512
#define BATCH 32
#define HW 4096  // 64*64

typedef float vfloat4 __attribute__((ext_vector_type(4)));

// One WAVE per (b,c) plane: 4096 contiguous floats = 64 lanes x 16 float4.
// No LDS, no __syncthreads: 4 independent waves per block.
__global__ __launch_bounds__(256) void pool_kernel(const float* __restrict__ x,
                                                   float* __restrict__ pooled) {
    const int wave = threadIdx.x >> 6;
    const int lane = threadIdx.x & 63;
    const int plane = blockIdx.x * 4 + wave;  // 0 .. B*C-1
    const vfloat4* xp = (const vfloat4*)(x + (size_t)plane * HW);

    // 16 independent nontemporal 16B loads per lane -> deep load ILP
    float s0 = 0.f, s1 = 0.f, s2 = 0.f, s3 = 0.f;
#pragma unroll
    for (int i = 0; i < 4; ++i) {
        vfloat4 v0 = __builtin_nontemporal_load(&xp[lane + 64 * (4 * i + 0)]);
        vfloat4 v1 = __builtin_nontemporal_load(&xp[lane + 64 * (4 * i + 1)]);
        vfloat4 v2 = __builtin_nontemporal_load(&xp[lane + 64 * (4 * i + 2)]);
        vfloat4 v3 = __builtin_nontemporal_load(&xp[lane + 64 * (4 * i + 3)]);
        s0 += (v0.x + v0.y) + (v0.z + v0.w);
        s1 += (v1.x + v1.y) + (v1.z + v1.w);
        s2 += (v2.x + v2.y) + (v2.z + v2.w);
        s3 += (v3.x + v3.y) + (v3.z + v3.w);
    }
    float s = (s0 + s1) + (s2 + s3);

    // 64-lane butterfly reduce
#pragma unroll
    for (int off = 32; off > 0; off >>= 1) s += __shfl_down(s, off, 64);

    if (lane == 0) pooled[plane] = s * (1.0f / (float)HW);
}

// One block per batch row. Bottleneck (512->32, ReLU) then expansion (32->512, sigmoid).
__global__ __launch_bounds__(256) void mlp_kernel(const float* __restrict__ pooled,
                                                  const float* __restrict__ w1,
                                                  const float* __restrict__ b1,
                                                  const float* __restrict__ w2,
                                                  const float* __restrict__ b2,
                                                  float* __restrict__ out) {
    const int b = blockIdx.x;  // 0..31
    const int tid = threadIdx.x;

    __shared__ float sp[IN_DIM];
    __shared__ float sh[MID];

    sp[tid] = pooled[b * IN_DIM + tid];
    sp[tid + 256] = pooled[b * IN_DIM + tid + 256];
    __syncthreads();

    if (tid < MID) {
        float acc = b1[tid];
        const float4* wr = (const float4*)(w1 + tid * IN_DIM);
        const float4* spv = (const float4*)sp;
#pragma unroll 4
        for (int c = 0; c < IN_DIM / 4; ++c) {
            float4 w = wr[c];
            float4 p = spv[c];
            acc += w.x * p.x + w.y * p.y + w.z * p.z + w.w * p.w;
        }
        sh[tid] = fmaxf(acc, 0.f);
    }
    __syncthreads();

#pragma unroll
    for (int r = 0; r < 2; ++r) {
        const int o = tid + r * 256;
        float acc = b2[o];
        const float* wr = w2 + o * MID;
#pragma unroll
        for (int m = 0; m < MID; ++m) acc += sh[m] * wr[m];
        out[b * OUT_DIM + o] = 1.0f / (1.0f + expf(-acc));
    }
}

extern "C" void kernel_launch(void* const* d_in, const int* in_sizes, int n_in,
                              void* d_out, int out_size, void* d_ws, size_t ws_size,
                              hipStream_t stream) {
    const float* x  = (const float*)d_in[0];
    const float* w1 = (const float*)d_in[1];
    const float* b1 = (const float*)d_in[2];
    const float* w2 = (const float*)d_in[3];
    const float* b2 = (const float*)d_in[4];
    float* out = (float*)d_out;
    float* pooled = (float*)d_ws;  // BATCH*IN_DIM floats = 64 KiB

    pool_kernel<<<(BATCH * IN_DIM) / 4, 256, 0, stream>>>(x, pooled);
    mlp_kernel<<<BATCH, 256, 0, stream>>>(pooled, w1, b1, w2, b2, out);
}